// Round 7
// baseline (293.066 us; speedup 1.0000x reference)
//
#include <hip/hip_runtime.h>

#define BS    8
#define NCH   7
#define PX    409600     // 640*640
#define SBLK  160        // blocks per sample
#define ITER  5          // 160 blocks * 256 thr * 2 px * 5 iters = PX
#define EPSF  1e-6f

// hardware reciprocal (v_rcp_f32, ~1ulp)
__device__ __forceinline__ float sigf(float x) {
    return __builtin_amdgcn_rcpf(1.0f + __expf(-x));
}

__device__ __forceinline__ unsigned wred_u(unsigned v) {
    #pragma unroll
    for (int o = 32; o; o >>= 1) v += __shfl_down(v, o);
    return v;
}

__device__ __forceinline__ float wred_f(float v) {
    #pragma unroll
    for (int o = 32; o; o >>= 1) v += __shfl_down(v, o);
    return v;
}

// sums layout: sums[(b*7+ch)*3 + j]; ch 0..5 = L_s (sn,sp,sl), ch 6 = L_c (a0,a1,a2)

// =====================================================================================
// K1: THE single pass over all 196.6 MB, software-pipelined.
// grid (SBLK, BS), 256 thr, 2 px/thread/iter, ITER iterations, register double-buffer:
// iteration i+1's 15 loads are issued BEFORE iteration i is consumed.
// L_c computed with M == 1 (exact fast path; k_final repairs if ever wrong).
// =====================================================================================
__global__ __launch_bounds__(256, 4) void k_fat(const float* __restrict__ preds,
                                                const int* __restrict__ labels,
                                                const int* __restrict__ mask,
                                                unsigned* __restrict__ n_pos,
                                                unsigned* __restrict__ n_nz,
                                                float* __restrict__ sums) {
    int b = blockIdx.y;
    const float* pr = preds + (size_t)b * NCH * PX;
    const int*   lb = labels + (size_t)b * NCH * PX;
    const int*   mk = mask + (size_t)b * PX;

    unsigned pos = 0, nz = 0;
    float accC[3] = {0.f, 0.f, 0.f};   // a0,a1,a2 (ch6, M==1)
    float acc[18];
    #pragma unroll
    for (int j = 0; j < 18; j++) acc[j] = 0.f;

    // register double-buffer: [0]=mask, [1..7]=preds ch0..6, [8..14]=labels ch0..6
    float2 curf[8], nxtf[8];       // curf[0] unused pad; curf[1..7] = preds
    int2   curi[8], nxti[8];       // curi[0] = mask;      curi[1..7] = labels

    // stride between iterations: SBLK blocks worth of pixels
    const int istride = SBLK * 256 * 2;
    int base = (blockIdx.x * 256 + threadIdx.x) * 2;

    // ---- prologue: load iteration 0 ----
    curi[0] = *(const int2*)(mk + base);
    #pragma unroll
    for (int c = 0; c < 7; c++) {
        curf[1 + c] = *(const float2*)(pr + c * PX + base);
        curi[1 + c] = *(const int2*)(lb + c * PX + base);
    }

    #pragma unroll
    for (int it = 0; it < ITER; it++) {
        // ---- issue next iteration's 15 loads (fire before consuming cur) ----
        if (it + 1 < ITER) {
            int nb = base + istride;
            nxti[0] = *(const int2*)(mk + nb);
            #pragma unroll
            for (int c = 0; c < 7; c++) {
                nxtf[1 + c] = *(const float2*)(pr + c * PX + nb);
                nxti[1 + c] = *(const int2*)(lb + c * PX + nb);
            }
        }

        // ---- consume cur ----
        float ms[2] = {(float)curi[0].x, (float)curi[0].y};
        float p6[2] = {curf[7].x, curf[7].y};
        float l6[2] = {(float)curi[7].x, (float)curi[7].y};
        float W[2];
        #pragma unroll
        for (int u = 0; u < 2; u++) {
            float pn = sigf(p6[u]) * ms[u];
            bool P = (pn >= 0.5f);
            pos += P;
            nz  += (!P && __float_as_uint(pn) != 0u);
            W[u] = P ? 1.0f : 0.0f;
            float ln = l6[u] * ms[u];
            accC[0] += pn * ln;     // M == 1 fast path
            accC[1] += pn * pn;
            accC[2] += ln;          // ln*ln == ln (0/1)
        }
        #pragma unroll
        for (int c = 0; c < 6; c++) {
            float ps[2] = {curf[1 + c].x, curf[1 + c].y};
            float ls[2] = {(float)curi[1 + c].x, (float)curi[1 + c].y};
            #pragma unroll
            for (int u = 0; u < 2; u++) {
                float s = sigf(ps[u]);
                float lw = ls[u] * W[u];
                acc[c]      += s * lw;        // sn
                acc[6 + c]  += s * s * W[u];  // sp
                acc[12 + c] += lw;            // sl
            }
        }

        // ---- rotate buffers ----
        if (it + 1 < ITER) {
            #pragma unroll
            for (int j = 0; j < 8; j++) { curf[j] = nxtf[j]; curi[j] = nxti[j]; }
            base += istride;
        }
    }

    // ---- block reduction: 21 floats + 2 uints ----
    __shared__ float red[4][21];
    __shared__ unsigned ws2[2][4];
    int lane = threadIdx.x & 63, wid = threadIdx.x >> 6;
    #pragma unroll
    for (int j = 0; j < 18; j++) {
        float v = wred_f(acc[j]);
        if (lane == 0) red[wid][j] = v;
    }
    #pragma unroll
    for (int j = 0; j < 3; j++) {
        float v = wred_f(accC[j]);
        if (lane == 0) red[wid][18 + j] = v;
    }
    unsigned pv = wred_u(pos), zv = wred_u(nz);
    if (lane == 0) { ws2[0][wid] = pv; ws2[1][wid] = zv; }
    __syncthreads();
    if (threadIdx.x < 21) {
        float tot = red[0][threadIdx.x] + red[1][threadIdx.x] +
                    red[2][threadIdx.x] + red[3][threadIdx.x];
        int j = threadIdx.x;
        int idx = (j < 18) ? (((size_t)b * 7 + (j % 6)) * 3 + (j / 6))
                           : (((size_t)b * 7 + 6) * 3 + (j - 18));
        atomicAdd(&sums[idx], tot);
    }
    if (threadIdx.x == 64) {
        unsigned pt = ws2[0][0] + ws2[0][1] + ws2[0][2] + ws2[0][3];
        unsigned zt = ws2[1][0] + ws2[1][1] + ws2[1][2] + ws2[1][3];
        if (pt) atomicAdd(&n_pos[b], pt);
        if (zt) atomicAdd(&n_nz[b], zt);
    }
}

// =====================================================================================
// K2: single block. Per-sample OHEM check; fast path (always, for this data): M == 1,
// sums already exact. Slow path kept exact (4-level LDS radix select + recompute).
// Then dice + means -> 3 outputs.
// =====================================================================================
__global__ __launch_bounds__(256) void k_final(const float* __restrict__ preds,
                                               const int* __restrict__ labels,
                                               const int* __restrict__ mask,
                                               const unsigned* __restrict__ n_pos,
                                               const unsigned* __restrict__ n_nz,
                                               const float* __restrict__ sums,
                                               float* __restrict__ out) {
    __shared__ float fr[BS * 21];
    if (threadIdx.x < BS * 21) fr[threadIdx.x] = sums[threadIdx.x];
    __syncthreads();

    __shared__ unsigned hist[256];
    __shared__ unsigned sh_sel, sh_rem;
    __shared__ float red[4][3];

    for (int b = 0; b < BS; b++) {
        unsigned np_ = n_pos[b];
        unsigned k = np_ * 3u;
        unsigned nneg = (unsigned)PX - np_;
        bool active = (nneg > k) && (k > 0u);
        if (!active || k > n_nz[b]) continue;   // M == 1: fr already exact

        // ---- slow path (never taken for this data, exact): radix select thr ----
        const float* pr = preds + ((size_t)b * NCH + 6) * PX;
        const int*   lb = labels + ((size_t)b * NCH + 6) * PX;
        const int*   mk = mask + (size_t)b * PX;
        unsigned prefix = 0u, krem = k;
        const unsigned masks[4] = {0x00000000u, 0xFF000000u, 0xFFFF0000u, 0xFFFFFF00u};
        for (int lv = 0; lv < 4; lv++) {
            int shift = 24 - 8 * lv;
            unsigned msk = masks[lv];
            hist[threadIdx.x] = 0u;
            __syncthreads();
            for (int g = threadIdx.x; g < PX / 4; g += 256) {
                int px = g * 4;
                float4 p4 = *(const float4*)(pr + px);
                int4   m4 = *(const int4*)(mk + px);
                float pa[4] = {p4.x, p4.y, p4.z, p4.w};
                float mm[4] = {(float)m4.x, (float)m4.y, (float)m4.z, (float)m4.w};
                #pragma unroll
                for (int u = 0; u < 4; u++) {
                    float pn = sigf(pa[u]) * mm[u];
                    if (pn < 0.5f) {
                        unsigned bits = __float_as_uint(pn);
                        if ((bits & msk) == prefix)
                            atomicAdd(&hist[(bits >> shift) & 0xFFu], 1u);
                    }
                }
            }
            __syncthreads();
            if (threadIdx.x == 0) {
                unsigned acc = 0, rem = krem, sel = 0;
                for (int i = 255; i >= 0; i--) {
                    acc += hist[i];
                    if (acc >= krem) { sel = (unsigned)i; rem = krem - (acc - hist[i]); break; }
                }
                sh_sel = sel; sh_rem = rem;
            }
            __syncthreads();
            prefix |= (sh_sel << shift);
            krem = sh_rem;
            __syncthreads();
        }
        float thr = __uint_as_float(prefix);

        float a0 = 0.f, a1 = 0.f, a2 = 0.f;
        for (int g = threadIdx.x; g < PX / 4; g += 256) {
            int px = g * 4;
            float4 p4 = *(const float4*)(pr + px);
            int4   l4 = *(const int4*)(lb + px);
            int4   m4 = *(const int4*)(mk + px);
            float pa[4] = {p4.x, p4.y, p4.z, p4.w};
            float la[4] = {(float)l4.x, (float)l4.y, (float)l4.z, (float)l4.w};
            float mm[4] = {(float)m4.x, (float)m4.y, (float)m4.z, (float)m4.w};
            #pragma unroll
            for (int u = 0; u < 4; u++) {
                float pn = sigf(pa[u]) * mm[u];
                float Mi = (pn >= thr) ? 1.0f : 0.0f;
                float ln = la[u] * mm[u];
                a0 += pn * ln * Mi;
                a1 += pn * pn * Mi;
                a2 += ln * Mi;
            }
        }
        int lane = threadIdx.x & 63, wid = threadIdx.x >> 6;
        float v0 = wred_f(a0), v1 = wred_f(a1), v2 = wred_f(a2);
        if (lane == 0) { red[wid][0] = v0; red[wid][1] = v1; red[wid][2] = v2; }
        __syncthreads();
        if (threadIdx.x < 3) {
            fr[(b * 7 + 6) * 3 + threadIdx.x] =
                red[0][threadIdx.x] + red[1][threadIdx.x] +
                red[2][threadIdx.x] + red[3][threadIdx.x];
        }
        __syncthreads();
    }

    if (threadIdx.x == 0) {
        float Lc = 0.f, Ls = 0.f;
        #pragma unroll
        for (int b = 0; b < BS; b++) {
            const float* s6 = fr + (b * 7 + 6) * 3;
            Lc += 1.0f - (2.0f * s6[0]) / (s6[1] + s6[2] + EPSF);
            float acc = 0.f;
            #pragma unroll
            for (int c = 0; c < 6; c++) {
                const float* sc = fr + (b * 7 + c) * 3;
                acc += (2.0f * sc[0]) / (sc[1] + sc[2] + EPSF);
            }
            Ls += 1.0f - acc * (1.0f / 6.0f);
        }
        float lc_m = Lc * (1.0f / (float)BS);
        float ls_m = Ls * (1.0f / (float)BS);
        out[0] = lc_m;
        out[1] = ls_m;
        out[2] = 0.7f * lc_m + 0.3f * ls_m;
    }
}

extern "C" void kernel_launch(void* const* d_in, const int* in_sizes, int n_in,
                              void* d_out, int out_size, void* d_ws, size_t ws_size,
                              hipStream_t stream) {
    const float* preds = (const float*)d_in[0];
    const int* labels  = (const int*)d_in[1];
    const int* mask    = (const int*)d_in[2];
    float* out = (float*)d_out;

    unsigned* n_pos = (unsigned*)d_ws;           // BS
    unsigned* n_nz  = n_pos + BS;                // BS
    float*    sums  = (float*)(n_nz + BS);       // BS*21

    hipMemsetAsync(d_ws, 0, (2 * BS + BS * 21) * sizeof(unsigned), stream);

    hipLaunchKernelGGL(k_fat, dim3(SBLK, BS), dim3(256), 0, stream,
                       preds, labels, mask, n_pos, n_nz, sums);

    hipLaunchKernelGGL(k_final, dim3(1), dim3(256), 0, stream,
                       preds, labels, mask, n_pos, n_nz, sums, out);
}